// Round 1
// baseline (40.803 us; speedup 1.0000x reference)
//
#include <hip/hip_runtime.h>

// NoiseLearnModule: out = x + where(valid, eps * sigmoid(params[f, bin]) * 0.1, 0)
// bin = searchsorted(bins[f], x, side='right') - 1 ; valid = 0 <= bin < 16
// Shapes: x,eps [65536,256] f32; bins [256,17] f32; params [256*16] f32.

#define NFEAT 256
#define NBINS 16
#define NEDGE 17
#define NOISE_SCALE 0.1f

__global__ __launch_bounds__(256) void noise_learn_kernel(
    const float* __restrict__ x,
    const float* __restrict__ bins,
    const float* __restrict__ eps,
    const float* __restrict__ params,
    float* __restrict__ out,
    int total4)
{
    // Transposed LDS tables: lane (feature) is the fast axis -> conflict-free.
    __shared__ float s_bins[NEDGE][NFEAT];   // 17*256*4 = 17408 B
    __shared__ float s_scale[NBINS][NFEAT];  // 16*256*4 = 16384 B

    const int t = threadIdx.x;  // block is exactly 256 threads == NFEAT

    // Stage bin edges transposed: s_bins[e][f] = bins[f*17 + e]
    #pragma unroll
    for (int e = 0; e < NEDGE; ++e)
        s_bins[e][t] = bins[t * NEDGE + e];

    // Stage sigmoid(params) transposed: s_scale[k][f] = sigmoid(params[f*16+k])
    #pragma unroll
    for (int k = 0; k < NBINS; ++k) {
        float p = params[t * NBINS + k];
        s_scale[k][t] = 1.0f / (1.0f + expf(-p));
    }
    __syncthreads();

    const int gid = blockIdx.x * 256 + t;
    const int stride = gridDim.x * 256;      // multiple of 64 -> f loop-invariant
    const int fbase = (gid & 63) * 4;        // this thread's 4 features

    for (int g = gid; g < total4; g += stride) {
        const float4 xv = reinterpret_cast<const float4*>(x)[g];
        const float4 ev = reinterpret_cast<const float4*>(eps)[g];

        int c0 = 0, c1 = 0, c2 = 0, c3 = 0;  // count of edges <= x (searchsorted 'right')
        #pragma unroll
        for (int e = 0; e < NEDGE; ++e) {
            const float4 be = *reinterpret_cast<const float4*>(&s_bins[e][fbase]);
            c0 += (be.x <= xv.x) ? 1 : 0;
            c1 += (be.y <= xv.y) ? 1 : 0;
            c2 += (be.z <= xv.z) ? 1 : 0;
            c3 += (be.w <= xv.w) ? 1 : 0;
        }

        float4 ov;
        {
            const int idx = c0 - 1;
            const int jc = idx < 0 ? 0 : (idx > NBINS - 1 ? NBINS - 1 : idx);
            const float sc = s_scale[jc][fbase + 0];
            ov.x = xv.x + ((idx >= 0 && idx < NBINS) ? ev.x * sc * NOISE_SCALE : 0.0f);
        }
        {
            const int idx = c1 - 1;
            const int jc = idx < 0 ? 0 : (idx > NBINS - 1 ? NBINS - 1 : idx);
            const float sc = s_scale[jc][fbase + 1];
            ov.y = xv.y + ((idx >= 0 && idx < NBINS) ? ev.y * sc * NOISE_SCALE : 0.0f);
        }
        {
            const int idx = c2 - 1;
            const int jc = idx < 0 ? 0 : (idx > NBINS - 1 ? NBINS - 1 : idx);
            const float sc = s_scale[jc][fbase + 2];
            ov.z = xv.z + ((idx >= 0 && idx < NBINS) ? ev.z * sc * NOISE_SCALE : 0.0f);
        }
        {
            const int idx = c3 - 1;
            const int jc = idx < 0 ? 0 : (idx > NBINS - 1 ? NBINS - 1 : idx);
            const float sc = s_scale[jc][fbase + 3];
            ov.w = xv.w + ((idx >= 0 && idx < NBINS) ? ev.w * sc * NOISE_SCALE : 0.0f);
        }

        reinterpret_cast<float4*>(out)[g] = ov;
    }
}

extern "C" void kernel_launch(void* const* d_in, const int* in_sizes, int n_in,
                              void* d_out, int out_size, void* d_ws, size_t ws_size,
                              hipStream_t stream) {
    const float* x      = (const float*)d_in[0];
    const float* bins   = (const float*)d_in[1];
    const float* eps    = (const float*)d_in[2];
    const float* params = (const float*)d_in[3];
    float* out = (float*)d_out;

    const int total4 = out_size / 4;  // 65536*256/4 = 4,194,304 float4 groups
    dim3 block(256);
    dim3 grid(2048);                  // 8 blocks/CU nominal; grid-stride covers rest
    noise_learn_kernel<<<grid, block, 0, stream>>>(x, bins, eps, params, out, total4);
}